// Round 17
// baseline (192.428 us; speedup 1.0000x reference)
//
#include <hip/hip_runtime.h>
#include <math.h>

#define KS 21
#define K2 441
#define NB 8
#define PPI 4096
#define NPIX 65536
#define STR 72                     // LDS activation row stride (u16)
#define XW 276
#define XDIM 276
#define XRS (XDIM * 8)             // xpad row stride bytes
#define XIMG ((size_t)XDIM * XDIM * 8)   // bytes per padded image
#define XPAD_OFF 200704            // ws byte offset of xpad (4K aligned)

typedef unsigned short u16;
typedef unsigned int u32;
typedef short short8v __attribute__((ext_vector_type(8)));
typedef float f32x4 __attribute__((ext_vector_type(4)));
typedef float f32x16 __attribute__((ext_vector_type(16)));
typedef u32 u32x2v __attribute__((ext_vector_type(2)));

// ws layout (u16 units): layer frags 17*4096 | wout frags 28672 | bout 448 f32
#define WOUT_OFF 69632
#define BOUT_BYTE 196608

// ---- fallback (r16) kernel constants ----
#define LDS_HBUF  0
#define LDS_XS    36864
#define LDS_BSH   109728
#define LDS_SBUF  111520
#define LDS_OBUF  113568
#define LDS_TOTAL 119712
#define XROWS 33

// LDS-only barrier: does NOT drain outstanding global stores (vmcnt).
#define BAR_LDS()                                                   \
    do {                                                            \
        asm volatile("s_waitcnt lgkmcnt(0)" ::: "memory");          \
        __builtin_amdgcn_s_barrier();                               \
        __builtin_amdgcn_sched_barrier(0);                          \
    } while (0)

__device__ __forceinline__ u16 f2bf(float x)
{
    union { float f; u32 u; } c; c.f = x;
    u32 r = c.u + 0x7FFF + ((c.u >> 16) & 1);
    return (u16)(r >> 16);
}
__device__ __forceinline__ float bflo(u32 w)
{ union { u32 u; float f; } c; c.u = w << 16; return c.f; }
__device__ __forceinline__ float bfhi(u32 w)
{ union { u32 u; float f; } c; c.u = w & 0xffff0000u; return c.f; }

__device__ __forceinline__ int reflect256(int v)
{
    v = (v < 0) ? -v : v;
    return (v > 255) ? (510 - v) : v;
}

// bijective XCD swizzles
__device__ __forceinline__ int xcd_swz1024(int i)   // 1024-block grids
{
    return ((i & 7) << 7) | (i >> 3);
}
__device__ __forceinline__ int xcd_swz256(int i)    // 256-block grids
{
    return ((i & 7) << 5) | (i >> 3);
}

// xs (fallback LDS path) swizzled byte offset
__device__ __forceinline__ u32 xs_off(int row, int col)
{
    u32 off = (u32)row * XRS + (u32)col * 8;
    return off ^ ((((u32)col >> 4) & 3) << 3);
}

// ---------------------------------------------------------------- prep ----
__global__ void prep_kernel(const float* __restrict__ w_in,
                            const float* __restrict__ rw1,
                            const float* __restrict__ rw2,
                            const float* __restrict__ w_out,
                            const float* __restrict__ b_out,
                            u16* __restrict__ wsu, float* __restrict__ bout)
{
    int idx = blockIdx.x * 256 + threadIdx.x;
    if (idx < 69632) {
        int u = idx & 4095;
        int j = u & 7, lane = (u >> 3) & 63, frag = (u >> 9) & 7;
        int kk = frag >> 2, nt = frag & 3, layer = idx >> 12;
        int i = kk * 32 + (lane >> 4) * 8 + j;      // K (input ch)
        int o = nt * 16 + (lane & 15);              // N (output ch)
        const float* src;
        if (layer == 0) src = w_in;
        else if (layer & 1) src = rw1 + ((layer - 1) >> 1) * 4096;
        else src = rw2 + ((layer - 2) >> 1) * 4096;
        wsu[idx] = f2bf(src[o * 64 + i]);
    } else if (idx < 69632 + 28672) {
        int u = idx - 69632;
        int j = u & 7, lane = (u >> 3) & 63, t6 = u >> 9;   // 0..55
        int t = t6 % 14, kk = t6 / 14;
        int tap = t * 32 + (lane & 31);
        int i = kk * 16 + (lane >> 5) * 8 + j;
        wsu[idx] = f2bf((tap < K2) ? w_out[tap * 64 + i] : 0.f);
    } else if (idx < 69632 + 28672 + 448) {
        int tap = idx - (69632 + 28672);
        bout[tap] = (tap < K2) ? b_out[tap] : -100.f;
    }
}

// ----------------------------------------------------------------- pad ----
// Pre-reflected, bf16-4ch-packed x: xpad[b][row 0..275][col 0..275], 8B/elem.
// Element (row,col) = x[:, reflect(row-10), reflect(col-10)].
__global__ void pad_kernel(const float* __restrict__ x, char* __restrict__ xpad)
{
    int idx = blockIdx.x * 256 + threadIdx.x;
    if (idx >= 16 * XDIM * XDIM) return;
    int b = idx / (XDIM * XDIM);
    int r = idx - b * (XDIM * XDIM);
    int row = r / XDIM, col = r - row * XDIM;
    int sr = reflect256(row - 10), sc = reflect256(col - 10);
    const float* xp = x + (size_t)b * 3 * 65536 + sr * 256 + sc;
    u32 w0 = (u32)f2bf(xp[0]) | ((u32)f2bf(xp[65536]) << 16);
    u32 w1 = (u32)f2bf(xp[2 * 65536]);
    u32x2v wv; wv[0] = w0; wv[1] = w1;
    *(u32x2v*)(xpad + (size_t)b * XIMG + (size_t)row * XRS + col * 8) = wv;
}

// ------------------------------------------------------------- layers ----
template <int MODE>
__device__ __forceinline__ void do_layer(u16* hb, const u16* __restrict__ wb,
                                         const float* __restrict__ bias,
                                         float* hreg, int aoff, int wbase,
                                         int c, int g, int lane)
{
    short8v a0 = *(const short8v*)(hb + aoff);
    short8v a1 = *(const short8v*)(hb + aoff + 32);
#pragma unroll
    for (int nt = 0; nt < 4; ++nt) {
        f32x4 acc = {};
        short8v b0 = *(const short8v*)(wb + ((nt)     * 64 + lane) * 8);
        short8v b1 = *(const short8v*)(wb + ((4 + nt) * 64 + lane) * 8);
        acc = __builtin_amdgcn_mfma_f32_16x16x32_bf16(a0, b0, acc, 0, 0, 0);
        acc = __builtin_amdgcn_mfma_f32_16x16x32_bf16(a1, b1, acc, 0, 0, 0);
        const float bv = bias[nt * 16 + c];
#pragma unroll
        for (int r = 0; r < 4; ++r) {
            float v = acc[r] + bv;
            if (MODE == 1) v = fmaxf(v, 0.f);
            if (MODE == 2) { v += hreg[nt * 4 + r]; hreg[nt * 4 + r] = v; }
            if (MODE == 0) hreg[nt * 4 + r] = v;
            hb[(wbase + g * 4 + r) * STR + nt * 16 + c] = f2bf(v);
        }
    }
}

// ------------------------------------- small-block fused trunk (primary) --
// 64 px (one low-res row) per block, 4 waves, ~13KB static LDS ->
// up to 8 blocks/CU (32 waves/CU). x window read from global xpad (L2).
__launch_bounds__(256, 8)
__global__ void trunk_small(const float* __restrict__ z,
                            const char* __restrict__ xpad,
                            const float* __restrict__ b_in,
                            const float* __restrict__ rb1,
                            const float* __restrict__ rb2,
                            const u16* __restrict__ wsu,
                            const float* __restrict__ bout,
                            float* __restrict__ out,
                            float* __restrict__ kout)
{
    __shared__ __align__(16) u16 hbuf[64 * STR];   // 9216 B
    __shared__ float bsh[448];
    __shared__ float sbuf[4][32];
    __shared__ float obuf[4][3][32];

    const int tid = threadIdx.x, lane = tid & 63, wave = tid >> 6;  // 0..3
    const int pix0 = xcd_swz1024(blockIdx.x) * 64;
    const int b = pix0 >> 12, rem0 = pix0 & 4095;
    const int hl = rem0 >> 6;                     // single low-res row

    // ---- stage z -> hbuf (bf16); thread (p,g) stages px p, 16 channels ----
    {
        const int p = tid & 63, i0 = (tid >> 6) * 16;
        const float* zp = z + ((size_t)b * 64 + i0) * PPI + rem0 + p;
        u32* dst = (u32*)hbuf + p * (STR / 2) + i0 / 2;
#pragma unroll
        for (int i = 0; i < 16; i += 2) {
            float v0 = zp[(size_t)i * PPI];
            float v1 = zp[(size_t)(i + 1) * PPI];
            dst[i / 2] = (u32)f2bf(v0) | ((u32)f2bf(v1) << 16);
        }
    }
    for (int u = tid; u < 448; u += 256) bsh[u] = bout[u];   // strided!
    BAR_LDS();

    // ---- 17-layer trunk, wave-private rows [wave*16, wave*16+16) ----
    const int c16 = lane & 15, g4 = lane >> 4;
    const int wbase = wave * 16;
    const int aoff = (wbase + c16) * STR + g4 * 8;
    float hreg[16];

    do_layer<0>(hbuf, wsu, b_in, hreg, aoff, wbase, c16, g4, lane);
#pragma unroll 1
    for (int l = 0; l < NB; ++l) {
        do_layer<1>(hbuf, wsu + (size_t)(1 + 2 * l) * 4096, rb1 + l * 64,
                    hreg, aoff, wbase, c16, g4, lane);
        do_layer<2>(hbuf, wsu + (size_t)(2 + 2 * l) * 4096, rb2 + l * 64,
                    hreg, aoff, wbase, c16, g4, lane);
    }
    BAR_LDS();   // pass 1 reads other waves' h rows

    // ---- pass 1 (swapped operands, 32x32x16): D[tap][px], px on lane&31 ----
    const int c32 = lane & 31, hi2 = lane >> 5;
    const int wavepx = (wave >> 1) * 32;       // 0 or 32
    const int tbase = (wave & 1) * 7;          // 7 of 14 tap-tiles

    short8v bh[4];
#pragma unroll
    for (int kk = 0; kk < 4; ++kk)
        bh[kk] = *(const short8v*)(hbuf + (wavepx + c32) * STR + kk * 16 + hi2 * 8);

    float ssum = 0.f;
    u32 epack[56];
    const u16* wob = wsu + WOUT_OFF;
#pragma unroll
    for (int ti = 0; ti < 7; ++ti) {
        const int t = tbase + ti;
        f32x16 acc = {};
#pragma unroll
        for (int kk = 0; kk < 4; ++kk) {
            short8v aw = *(const short8v*)(wob + ((kk * 14 + t) * 64 + lane) * 8);
            acc = __builtin_amdgcn_mfma_f32_32x32x16_bf16(aw, bh[kk], acc, 0, 0, 0);
        }
#pragma unroll
        for (int rr = 0; rr < 8; ++rr) {
            const int r0 = 2 * rr;
            const int tap0 = t * 32 + (r0 & 3) + 8 * (r0 >> 2) + 4 * hi2;
            float e0 = __expf(acc[r0] + bsh[tap0]);
            float e1 = __expf(acc[r0 + 1] + bsh[tap0 + 1]);
            ssum += e0 + e1;
            epack[ti * 8 + rr] = (u32)f2bf(e0) | ((u32)f2bf(e1) << 16);
        }
    }
    ssum += __shfl_xor(ssum, 32);              // combine hi2 tap-halves
    if (lane < 32) sbuf[wave][lane] = ssum;
    BAR_LDS();
    const float inv_s = 1.f / (ssum + sbuf[wave ^ 1][c32]);

    // ---- pass 2 + fused apply: p stores + xpad L2 reads ----
    const int pxl = wavepx + c32;              // == wl (block = one hl row)
    float* kbase = kout + (size_t)b * K2 * PPI + rem0 + pxl;
    const char* xb = xpad + (size_t)b * XIMG + (size_t)(hl * 4) * XRS + pxl * 32;
    float oacc0 = 0.f, oacc1 = 0.f, oacc2 = 0.f;

#pragma unroll
    for (int ti = 0; ti < 7; ++ti) {
        const int t = tbase + ti;
        int tap = t * 32 + 4 * hi2;
        int ky = tap / KS;
        int kx = tap - ky * KS;
#pragma unroll
        for (int rr = 0; rr < 8; ++rr) {
            const u32 ep = epack[ti * 8 + rr];
            float p0 = bflo(ep) * inv_s;
            float p1 = bfhi(ep) * inv_s;
            if (tap < K2) {
                kbase[(size_t)tap * PPI] = p0;
                u32x2v wv = *(const u32x2v*)(xb + ky * XRS + kx * 8);
                oacc0 = fmaf(p0, bflo(wv[0]), oacc0);
                oacc1 = fmaf(p0, bfhi(wv[0]), oacc1);
                oacc2 = fmaf(p0, bflo(wv[1]), oacc2);
            }
            tap += 1; kx += 1; if (kx >= KS) { kx -= KS; ky += 1; }
            if (tap < K2) {
                kbase[(size_t)tap * PPI] = p1;
                u32x2v wv = *(const u32x2v*)(xb + ky * XRS + kx * 8);
                oacc0 = fmaf(p1, bflo(wv[0]), oacc0);
                oacc1 = fmaf(p1, bfhi(wv[0]), oacc1);
                oacc2 = fmaf(p1, bflo(wv[1]), oacc2);
            }
            const int d = (rr & 1) ? 5 : 1;
            tap += d; kx += d; if (kx >= KS) { kx -= KS; ky += 1; }
        }
    }

    // ---- out reduction: tap-halves (xor32), then wave-pair via LDS ----
    oacc0 += __shfl_xor(oacc0, 32);
    oacc1 += __shfl_xor(oacc1, 32);
    oacc2 += __shfl_xor(oacc2, 32);
    if (lane < 32) {
        obuf[wave][0][lane] = oacc0;
        obuf[wave][1][lane] = oacc1;
        obuf[wave][2][lane] = oacc2;
    }
    BAR_LDS();
    if ((wave & 1) == 0 && lane < 32) {
        const int o = rem0 + wavepx + lane;
#pragma unroll
        for (int cch = 0; cch < 3; ++cch) {
            float v = obuf[wave][cch][lane] + obuf[wave + 1][cch][lane];
            out[((size_t)b * 3 + cch) * PPI + o] = v;
        }
    }
}

// --------------------------- fallback kernel (r16, xs in LDS) -------------
__launch_bounds__(1024, 1)
__global__ void trunk_kernel(const float* __restrict__ z,
                             const float* __restrict__ x,
                             const float* __restrict__ b_in,
                             const float* __restrict__ rb1,
                             const float* __restrict__ rb2,
                             const u16* __restrict__ wsu,
                             const float* __restrict__ bout,
                             float* __restrict__ out,
                             float* __restrict__ kout)
{
    extern __shared__ __align__(16) char smem[];
    u16*   hbuf = (u16*)(smem + LDS_HBUF);
    char*  xsb  = smem + LDS_XS;
    float* bsh  = (float*)(smem + LDS_BSH);
    float* sbuf = (float*)(smem + LDS_SBUF);
    float* obuf = (float*)(smem + LDS_OBUF);

    const int tid = threadIdx.x, lane = tid & 63, wave = tid >> 6;
    const int pix0 = xcd_swz256(blockIdx.x) * 256;
    const int b = pix0 >> 12, rem0 = pix0 & 4095;
    const int hl0 = rem0 >> 6;

    {
        const int p = tid & 255, i0 = (tid >> 8) * 16;
        const float* zp = z + ((size_t)b * 64 + i0) * PPI + rem0 + p;
        u32* dst = (u32*)hbuf + p * (STR / 2) + i0 / 2;
#pragma unroll
        for (int i = 0; i < 16; i += 2) {
            float v0 = zp[(size_t)i * PPI];
            float v1 = zp[(size_t)(i + 1) * PPI];
            dst[i / 2] = (u32)f2bf(v0) | ((u32)f2bf(v1) << 16);
        }
    }
    for (int u = tid; u < XROWS * XW; u += 1024) {
        int rr = u / XW, c = u - rr * XW;
        int row = reflect256(hl0 * 4 + rr - 10);
        int xcol = reflect256(c - 10);
        const float* xp = x + (size_t)b * 3 * 65536 + row * 256 + xcol;
        u32 w0 = (u32)f2bf(xp[0]) | ((u32)f2bf(xp[65536]) << 16);
        u32 w1 = (u32)f2bf(xp[2 * 65536]);
        u32x2v wv; wv[0] = w0; wv[1] = w1;
        *(u32x2v*)(xsb + xs_off(rr, c)) = wv;
    }
    if (tid < 448) bsh[tid] = bout[tid];
    BAR_LDS();

    const int c16 = lane & 15, g4 = lane >> 4;
    const int wbase = wave * 16;
    const int aoff = (wbase + c16) * STR + g4 * 8;
    float hreg[16];

    do_layer<0>(hbuf, wsu, b_in, hreg, aoff, wbase, c16, g4, lane);
#pragma unroll 1
    for (int l = 0; l < NB; ++l) {
        do_layer<1>(hbuf, wsu + (size_t)(1 + 2 * l) * 4096, rb1 + l * 64,
                    hreg, aoff, wbase, c16, g4, lane);
        do_layer<2>(hbuf, wsu + (size_t)(2 + 2 * l) * 4096, rb2 + l * 64,
                    hreg, aoff, wbase, c16, g4, lane);
    }
    BAR_LDS();

    const int c32 = lane & 31, hi2 = lane >> 5;
    const int wavepx = (wave >> 1) * 32;
    const int tbase = (wave & 1) * 7;

    short8v bh[4];
#pragma unroll
    for (int kk = 0; kk < 4; ++kk)
        bh[kk] = *(const short8v*)(hbuf + (wavepx + c32) * STR + kk * 16 + hi2 * 8);

    float ssum = 0.f;
    u32 epack[56];
    const u16* wob = wsu + WOUT_OFF;
#pragma unroll
    for (int ti = 0; ti < 7; ++ti) {
        const int t = tbase + ti;
        f32x16 acc = {};
#pragma unroll
        for (int kk = 0; kk < 4; ++kk) {
            short8v aw = *(const short8v*)(wob + ((kk * 14 + t) * 64 + lane) * 8);
            acc = __builtin_amdgcn_mfma_f32_32x32x16_bf16(aw, bh[kk], acc, 0, 0, 0);
        }
#pragma unroll
        for (int rr = 0; rr < 8; ++rr) {
            const int r0 = 2 * rr;
            const int tap0 = t * 32 + (r0 & 3) + 8 * (r0 >> 2) + 4 * hi2;
            float e0 = __expf(acc[r0] + bsh[tap0]);
            float e1 = __expf(acc[r0 + 1] + bsh[tap0 + 1]);
            ssum += e0 + e1;
            epack[ti * 8 + rr] = (u32)f2bf(e0) | ((u32)f2bf(e1) << 16);
        }
    }
    ssum += __shfl_xor(ssum, 32);
    if (lane < 32) sbuf[wave * 32 + lane] = ssum;
    BAR_LDS();
    const float inv_s = 1.f / (ssum + sbuf[(wave ^ 1) * 32 + c32]);

    const int pxl = wavepx + c32;
    const int wl = pxl & 63, hlr = pxl >> 6;
    const int xcb4 = wl * 4;
    float* kbase = kout + (size_t)b * K2 * PPI + rem0 + pxl;
    float oacc0 = 0.f, oacc1 = 0.f, oacc2 = 0.f;

#pragma unroll
    for (int ti = 0; ti < 7; ++ti) {
        const int t = tbase + ti;
        int tap = t * 32 + 4 * hi2;
        int ky = tap / KS;
        int kx = tap - ky * KS;
#pragma unroll
        for (int rr = 0; rr < 8; ++rr) {
            const u32 ep = epack[ti * 8 + rr];
            float p0 = bflo(ep) * inv_s;
            float p1 = bfhi(ep) * inv_s;
            if (tap < K2) {
                kbase[(size_t)tap * PPI] = p0;
                u32x2v wv = *(const u32x2v*)(xsb + xs_off(hlr * 4 + ky, xcb4 + kx));
                oacc0 = fmaf(p0, bflo(wv[0]), oacc0);
                oacc1 = fmaf(p0, bfhi(wv[0]), oacc1);
                oacc2 = fmaf(p0, bflo(wv[1]), oacc2);
            }
            tap += 1; kx += 1; if (kx >= KS) { kx -= KS; ky += 1; }
            if (tap < K2) {
                kbase[(size_t)tap * PPI] = p1;
                u32x2v wv = *(const u32x2v*)(xsb + xs_off(hlr * 4 + ky, xcb4 + kx));
                oacc0 = fmaf(p1, bflo(wv[0]), oacc0);
                oacc1 = fmaf(p1, bfhi(wv[0]), oacc1);
                oacc2 = fmaf(p1, bflo(wv[1]), oacc2);
            }
            const int d = (rr & 1) ? 5 : 1;
            tap += d; kx += d; if (kx >= KS) { kx -= KS; ky += 1; }
        }
    }

    oacc0 += __shfl_xor(oacc0, 32);
    oacc1 += __shfl_xor(oacc1, 32);
    oacc2 += __shfl_xor(oacc2, 32);
    if (lane < 32) {
        obuf[(wave * 3 + 0) * 32 + lane] = oacc0;
        obuf[(wave * 3 + 1) * 32 + lane] = oacc1;
        obuf[(wave * 3 + 2) * 32 + lane] = oacc2;
    }
    BAR_LDS();
    if ((wave & 1) == 0 && lane < 32) {
        const int o = rem0 + wavepx + lane;
#pragma unroll
        for (int cch = 0; cch < 3; ++cch) {
            float v = obuf[(wave * 3 + cch) * 32 + lane] +
                      obuf[((wave + 1) * 3 + cch) * 32 + lane];
            out[((size_t)b * 3 + cch) * PPI + o] = v;
        }
    }
}

// ------------------------------------------------------------ launch -----
extern "C" void kernel_launch(void* const* d_in, const int* in_sizes, int n_in,
                              void* d_out, int out_size, void* d_ws, size_t ws_size,
                              hipStream_t stream)
{
    const float* x     = (const float*)d_in[0];
    const float* z     = (const float*)d_in[1];
    const float* w_in  = (const float*)d_in[2];
    const float* b_in  = (const float*)d_in[3];
    const float* rw1   = (const float*)d_in[4];
    const float* rb1   = (const float*)d_in[5];
    const float* rw2   = (const float*)d_in[6];
    const float* rb2   = (const float*)d_in[7];
    const float* w_out = (const float*)d_in[8];
    const float* b_out = (const float*)d_in[9];

    float* out  = (float*)d_out;
    float* kout = out + (size_t)16 * 3 * PPI;          // kernel output region
    u16*   wsu  = (u16*)d_ws;
    float* bout = (float*)((char*)d_ws + BOUT_BYTE);

    prep_kernel<<<(69632 + 28672 + 448 + 255) / 256, 256, 0, stream>>>(
        w_in, rw1, rw2, w_out, b_out, wsu, bout);

    const size_t need = (size_t)XPAD_OFF + 16 * XIMG;   // ~9.95 MB
    if (ws_size >= need) {
        char* xpad = (char*)d_ws + XPAD_OFF;
        pad_kernel<<<(16 * XDIM * XDIM + 255) / 256, 256, 0, stream>>>(x, xpad);
        trunk_small<<<NPIX / 64, 256, 0, stream>>>(
            z, xpad, b_in, rb1, rb2, wsu, bout, out, kout);
    } else {
        (void)hipFuncSetAttribute((const void*)trunk_kernel,
                                  hipFuncAttributeMaxDynamicSharedMemorySize,
                                  LDS_TOTAL);
        trunk_kernel<<<NPIX / 256, 1024, LDS_TOTAL, stream>>>(
            z, x, b_in, rb1, rb2, wsu, bout, out, kout);
    }
}

// Round 18
// 74.858 us; speedup vs baseline: 2.5706x; 2.5706x over previous
//
#include <hip/hip_runtime.h>
#include <math.h>

#define KS 21
#define K2 441
#define NB 8
#define PPI 4096
#define NPIX 65536
#define STR 72                     // LDS activation row stride (u16)
#define XW 276
#define BPX 256                    // pixels per block
#define NTH 1024                   // 16 waves
#define XROWS 33
#define XRS 2208                   // xs4 row stride bytes = 276 * 8
#define LOG2E 1.4426950408889634f

typedef unsigned short u16;
typedef unsigned int u32;
typedef short short8v __attribute__((ext_vector_type(8)));
typedef float f32x4 __attribute__((ext_vector_type(4)));
typedef float f32x16 __attribute__((ext_vector_type(16)));
typedef u32 u32x2v __attribute__((ext_vector_type(2)));

// ws layout (u16 units): layer frags 17*4096 | wout frags 28672 | bout 448 f32
#define WOUT_OFF 69632
#define BOUT_BYTE 196608

// dynamic-LDS byte offsets (16B aligned)
#define LDS_HBUF  0                // 256*72*2        = 36864
#define LDS_XS    36864            // 33*276*8        = 72864 -> ends 109728
#define LDS_BSH   109728           // 448*4           = 1792
#define LDS_SBUF  111520           // 16*32*4         = 2048
#define LDS_OBUF  113568           // 16*3*32*4       = 6144
#define LDS_TOTAL 119712

// LDS-only barrier: does NOT drain outstanding global stores (vmcnt).
#define BAR_LDS()                                                   \
    do {                                                            \
        asm volatile("s_waitcnt lgkmcnt(0)" ::: "memory");          \
        __builtin_amdgcn_s_barrier();                               \
        __builtin_amdgcn_sched_barrier(0);                          \
    } while (0)

__device__ __forceinline__ u16 f2bf(float x)
{
    union { float f; u32 u; } c; c.f = x;
    u32 r = c.u + 0x7FFF + ((c.u >> 16) & 1);
    return (u16)(r >> 16);
}
__device__ __forceinline__ float bflo(u32 w)
{ union { u32 u; float f; } c; c.u = w << 16; return c.f; }
__device__ __forceinline__ float bfhi(u32 w)
{ union { u32 u; float f; } c; c.u = w & 0xffff0000u; return c.f; }

// XCD-aware bijective swizzle (256 blocks): XCD x owns 32 consecutive blocks.
__device__ __forceinline__ int xcd_swz(int i)
{
    return ((i & 7) << 5) | (i >> 3);
}

// xs4 swizzled byte offset for element (row, col): 8B-aligned XOR swizzle
// on addr bits [4:3] -> spreads px-stride-4 reads across 16 banks (<=2-way).
__device__ __forceinline__ u32 xs_off(int row, int col)
{
    u32 off = (u32)row * XRS + (u32)col * 8;
    return off ^ ((((u32)col >> 4) & 3) << 3);
}

// ---------------------------------------------------------------- prep ----
// exp2-folding: w_out and b_out are pre-scaled by log2(e) so pass-1 uses the
// raw v_exp_f32 (2^x) with no per-element multiply.
__global__ void prep_kernel(const float* __restrict__ w_in,
                            const float* __restrict__ rw1,
                            const float* __restrict__ rw2,
                            const float* __restrict__ w_out,
                            const float* __restrict__ b_out,
                            u16* __restrict__ wsu, float* __restrict__ bout)
{
    int idx = blockIdx.x * 256 + threadIdx.x;
    if (idx < 69632) {
        int u = idx & 4095;
        int j = u & 7, lane = (u >> 3) & 63, frag = (u >> 9) & 7;
        int kk = frag >> 2, nt = frag & 3, layer = idx >> 12;
        int i = kk * 32 + (lane >> 4) * 8 + j;      // K (input ch)
        int o = nt * 16 + (lane & 15);              // N (output ch)
        const float* src;
        if (layer == 0) src = w_in;
        else if (layer & 1) src = rw1 + ((layer - 1) >> 1) * 4096;
        else src = rw2 + ((layer - 2) >> 1) * 4096;
        wsu[idx] = f2bf(src[o * 64 + i]);
    } else if (idx < 69632 + 28672) {
        int u = idx - 69632;
        int j = u & 7, lane = (u >> 3) & 63, t6 = u >> 9;   // 0..55
        int t = t6 % 14, kk = t6 / 14;
        int tap = t * 32 + (lane & 31);
        int i = kk * 16 + (lane >> 5) * 8 + j;
        wsu[idx] = f2bf((tap < K2) ? w_out[tap * 64 + i] * LOG2E : 0.f);
    } else if (idx < 69632 + 28672 + 448) {
        int tap = idx - (69632 + 28672);
        // padded taps: 2^-200 == 0 -> never pollute softmax sum
        bout[tap] = (tap < K2) ? b_out[tap] * LOG2E : -200.f;
    }
}

// ------------------------------------------------------------- fused -----
__device__ __forceinline__ int reflect256(int v)
{
    v = (v < 0) ? -v : v;
    return (v > 255) ? (510 - v) : v;
}

template <int MODE>
__device__ __forceinline__ void do_layer(u16* hb, const u16* __restrict__ wb,
                                         const float* __restrict__ bias,
                                         float* hreg, int aoff, int wbase,
                                         int c, int g, int lane)
{
    short8v a0 = *(const short8v*)(hb + aoff);
    short8v a1 = *(const short8v*)(hb + aoff + 32);
#pragma unroll
    for (int nt = 0; nt < 4; ++nt) {
        f32x4 acc = {};
        short8v b0 = *(const short8v*)(wb + ((nt)     * 64 + lane) * 8);
        short8v b1 = *(const short8v*)(wb + ((4 + nt) * 64 + lane) * 8);
        acc = __builtin_amdgcn_mfma_f32_16x16x32_bf16(a0, b0, acc, 0, 0, 0);
        acc = __builtin_amdgcn_mfma_f32_16x16x32_bf16(a1, b1, acc, 0, 0, 0);
        const float bv = bias[nt * 16 + c];
#pragma unroll
        for (int r = 0; r < 4; ++r) {
            float v = acc[r] + bv;
            if (MODE == 1) v = fmaxf(v, 0.f);
            if (MODE == 2) { v += hreg[nt * 4 + r]; hreg[nt * 4 + r] = v; }
            if (MODE == 0) hreg[nt * 4 + r] = v;
            hb[(wbase + g * 4 + r) * STR + nt * 16 + c] = f2bf(v);
        }
    }
}

__launch_bounds__(NTH, 1)
__global__ void trunk_kernel(const float* __restrict__ z,
                             const float* __restrict__ x,
                             const float* __restrict__ b_in,
                             const float* __restrict__ rb1,
                             const float* __restrict__ rb2,
                             const u16* __restrict__ wsu,
                             const float* __restrict__ bout,
                             float* __restrict__ out,
                             float* __restrict__ kout)
{
    extern __shared__ __align__(16) char smem[];
    u16*   hbuf = (u16*)(smem + LDS_HBUF);     // [256][STR] in-place acts
    char*  xsb  = smem + LDS_XS;               // [33][276][4ch u16] swizzled
    float* bsh  = (float*)(smem + LDS_BSH);    // [448]
    float* sbuf = (float*)(smem + LDS_SBUF);   // [16][32]
    float* obuf = (float*)(smem + LDS_OBUF);   // [16][3][32]

    const int tid = threadIdx.x, lane = tid & 63, wave = tid >> 6;  // 0..15
    const int pix0 = xcd_swz(blockIdx.x) * BPX;
    const int b = pix0 >> 12, rem0 = pix0 & 4095;
    const int hl0 = rem0 >> 6;

    // ---- stage z -> hbuf (bf16) ----
    {
        const int p = tid & 255, i0 = (tid >> 8) * 16;
        const float* zp = z + ((size_t)b * 64 + i0) * PPI + rem0 + p;
        u32* dst = (u32*)hbuf + p * (STR / 2) + i0 / 2;
#pragma unroll
        for (int i = 0; i < 16; i += 2) {
            float v0 = zp[(size_t)i * PPI];
            float v1 = zp[(size_t)(i + 1) * PPI];
            dst[i / 2] = (u32)f2bf(v0) | ((u32)f2bf(v1) << 16);
        }
    }
    // ---- stage reflected x: 4ch-packed b64 elements, swizzled ----
    for (int u = tid; u < XROWS * XW; u += NTH) {
        int rr = u / XW, c = u - rr * XW;
        int row = reflect256(hl0 * 4 + rr - 10);
        int xcol = reflect256(c - 10);
        const float* xp = x + (size_t)b * 3 * 65536 + row * 256 + xcol;
        u32 w0 = (u32)f2bf(xp[0]) | ((u32)f2bf(xp[65536]) << 16);
        u32 w1 = (u32)f2bf(xp[2 * 65536]);
        u32x2v wv; wv[0] = w0; wv[1] = w1;
        *(u32x2v*)(xsb + xs_off(rr, c)) = wv;
    }
    if (tid < 448) bsh[tid] = bout[tid];
    BAR_LDS();

    // ---- 17-layer trunk, wave-private rows [wave*16, wave*16+16) ----
    const int c16 = lane & 15, g4 = lane >> 4;
    const int wbase = wave * 16;
    const int aoff = (wbase + c16) * STR + g4 * 8;
    float hreg[16];

    do_layer<0>(hbuf, wsu, b_in, hreg, aoff, wbase, c16, g4, lane);
#pragma unroll 1
    for (int l = 0; l < NB; ++l) {
        do_layer<1>(hbuf, wsu + (size_t)(1 + 2 * l) * 4096, rb1 + l * 64,
                    hreg, aoff, wbase, c16, g4, lane);
        do_layer<2>(hbuf, wsu + (size_t)(2 + 2 * l) * 4096, rb2 + l * 64,
                    hreg, aoff, wbase, c16, g4, lane);
    }
    BAR_LDS();   // pass 1 reads other waves' h rows (LDS-only ordering)

    // ---- pass 1 (swapped operands, 32x32x16): D[tap][px], px on lane&31 ----
    const int c32 = lane & 31, hi2 = lane >> 5;
    const int wavepx = (wave >> 1) * 32;       // 0..224
    const int tbase = (wave & 1) * 7;          // 7 of 14 tap-tiles

    short8v bh[4];
#pragma unroll
    for (int kk = 0; kk < 4; ++kk)
        bh[kk] = *(const short8v*)(hbuf + (wavepx + c32) * STR + kk * 16 + hi2 * 8);

    float ssum = 0.f;
    u32 epack[56];
    const u16* wob = wsu + WOUT_OFF;
#pragma unroll
    for (int ti = 0; ti < 7; ++ti) {
        const int t = tbase + ti;
        f32x16 acc = {};
#pragma unroll
        for (int kk = 0; kk < 4; ++kk) {
            short8v aw = *(const short8v*)(wob + ((kk * 14 + t) * 64 + lane) * 8);
            acc = __builtin_amdgcn_mfma_f32_32x32x16_bf16(aw, bh[kk], acc, 0, 0, 0);
        }
#pragma unroll
        for (int rr = 0; rr < 8; ++rr) {
            const int r0 = 2 * rr;
            const int tap0 = t * 32 + (r0 & 3) + 8 * (r0 >> 2) + 4 * hi2;
            // logits pre-scaled by log2(e): raw v_exp_f32, no mul
            float e0 = __builtin_amdgcn_exp2f(acc[r0] + bsh[tap0]);
            float e1 = __builtin_amdgcn_exp2f(acc[r0 + 1] + bsh[tap0 + 1]);
            ssum += e0 + e1;
            epack[ti * 8 + rr] = (u32)f2bf(e0) | ((u32)f2bf(e1) << 16);
        }
    }
    ssum += __shfl_xor(ssum, 32);              // combine hi2 tap-halves
    if (lane < 32) sbuf[wave * 32 + lane] = ssum;
    BAR_LDS();
    const float inv_s = 1.f / (ssum + sbuf[(wave ^ 1) * 32 + c32]);

    // ---- pass 2 + fused apply: p stores + one ds_read_b64 per tap.
    // Guard hoisting: tap<K2 can only fail in tile t==13 -> wave-uniform
    // branch keeps the 13 full tiles guard-free.
    const int pxl = wavepx + c32;
    const int wl = pxl & 63, hlr = pxl >> 6;
    const int xcb4 = wl * 4;
    float* kbase = kout + (size_t)b * K2 * PPI + rem0 + pxl;
    float oacc0 = 0.f, oacc1 = 0.f, oacc2 = 0.f;

#pragma unroll
    for (int ti = 0; ti < 7; ++ti) {
        const int t = tbase + ti;
        int tap = t * 32 + 4 * hi2;
        int ky = tap / KS;
        int kx = tap - ky * KS;
        if (t != 13) {
#pragma unroll
            for (int rr = 0; rr < 8; ++rr) {
                const u32 ep = epack[ti * 8 + rr];
                float p0 = bflo(ep) * inv_s;
                float p1 = bfhi(ep) * inv_s;
                kbase[(size_t)tap * PPI] = p0;
                {
                    u32x2v wv = *(const u32x2v*)(xsb + xs_off(hlr * 4 + ky, xcb4 + kx));
                    oacc0 = fmaf(p0, bflo(wv[0]), oacc0);
                    oacc1 = fmaf(p0, bfhi(wv[0]), oacc1);
                    oacc2 = fmaf(p0, bflo(wv[1]), oacc2);
                }
                tap += 1; kx += 1; if (kx >= KS) { kx -= KS; ky += 1; }
                kbase[(size_t)tap * PPI] = p1;
                {
                    u32x2v wv = *(const u32x2v*)(xsb + xs_off(hlr * 4 + ky, xcb4 + kx));
                    oacc0 = fmaf(p1, bflo(wv[0]), oacc0);
                    oacc1 = fmaf(p1, bfhi(wv[0]), oacc1);
                    oacc2 = fmaf(p1, bflo(wv[1]), oacc2);
                }
                const int d = (rr & 1) ? 5 : 1;
                tap += d; kx += d; if (kx >= KS) { kx -= KS; ky += 1; }
            }
        } else {
#pragma unroll
            for (int rr = 0; rr < 8; ++rr) {
                const u32 ep = epack[ti * 8 + rr];
                float p0 = bflo(ep) * inv_s;
                float p1 = bfhi(ep) * inv_s;
                if (tap < K2) {
                    kbase[(size_t)tap * PPI] = p0;
                    u32x2v wv = *(const u32x2v*)(xsb + xs_off(hlr * 4 + ky, xcb4 + kx));
                    oacc0 = fmaf(p0, bflo(wv[0]), oacc0);
                    oacc1 = fmaf(p0, bfhi(wv[0]), oacc1);
                    oacc2 = fmaf(p0, bflo(wv[1]), oacc2);
                }
                tap += 1; kx += 1; if (kx >= KS) { kx -= KS; ky += 1; }
                if (tap < K2) {
                    kbase[(size_t)tap * PPI] = p1;
                    u32x2v wv = *(const u32x2v*)(xsb + xs_off(hlr * 4 + ky, xcb4 + kx));
                    oacc0 = fmaf(p1, bflo(wv[0]), oacc0);
                    oacc1 = fmaf(p1, bfhi(wv[0]), oacc1);
                    oacc2 = fmaf(p1, bflo(wv[1]), oacc2);
                }
                const int d = (rr & 1) ? 5 : 1;
                tap += d; kx += d; if (kx >= KS) { kx -= KS; ky += 1; }
            }
        }
    }

    // ---- out reduction: tap-halves (xor32), then wave-pair via LDS ----
    oacc0 += __shfl_xor(oacc0, 32);
    oacc1 += __shfl_xor(oacc1, 32);
    oacc2 += __shfl_xor(oacc2, 32);
    if (lane < 32) {
        obuf[(wave * 3 + 0) * 32 + lane] = oacc0;
        obuf[(wave * 3 + 1) * 32 + lane] = oacc1;
        obuf[(wave * 3 + 2) * 32 + lane] = oacc2;
    }
    BAR_LDS();
    if ((wave & 1) == 0 && lane < 32) {
        const int o = rem0 + wavepx + lane;
#pragma unroll
        for (int cch = 0; cch < 3; ++cch) {
            float v = obuf[(wave * 3 + cch) * 32 + lane] +
                      obuf[((wave + 1) * 3 + cch) * 32 + lane];
            out[((size_t)b * 3 + cch) * PPI + o] = v;
        }
    }
}

// ------------------------------------------------------------ launch -----
extern "C" void kernel_launch(void* const* d_in, const int* in_sizes, int n_in,
                              void* d_out, int out_size, void* d_ws, size_t ws_size,
                              hipStream_t stream)
{
    const float* x     = (const float*)d_in[0];
    const float* z     = (const float*)d_in[1];
    const float* w_in  = (const float*)d_in[2];
    const float* b_in  = (const float*)d_in[3];
    const float* rw1   = (const float*)d_in[4];
    const float* rb1   = (const float*)d_in[5];
    const float* rw2   = (const float*)d_in[6];
    const float* rb2   = (const float*)d_in[7];
    const float* w_out = (const float*)d_in[8];
    const float* b_out = (const float*)d_in[9];

    float* out  = (float*)d_out;
    float* kout = out + (size_t)16 * 3 * PPI;          // kernel output region
    u16*   wsu  = (u16*)d_ws;
    float* bout = (float*)((char*)d_ws + BOUT_BYTE);

    (void)hipFuncSetAttribute((const void*)trunk_kernel,
                              hipFuncAttributeMaxDynamicSharedMemorySize,
                              LDS_TOTAL);

    prep_kernel<<<(69632 + 28672 + 448 + 255) / 256, 256, 0, stream>>>(
        w_in, rw1, rw2, w_out, b_out, wsu, bout);

    trunk_kernel<<<NPIX / BPX, NTH, LDS_TOTAL, stream>>>(
        z, x, b_in, rb1, rb2, wsu, bout, out, kout);
}